// Round 1
// baseline (495.949 us; speedup 1.0000x reference)
//
#include <hip/hip_runtime.h>

#define N_EDGES   640000
#define NODE_DIM  128
#define EDGE_DIM  64
#define K_DIM     192
#define LDS_K     196   // pad 192 -> 196: row stride 392 B == 2 banks mod 32 -> 2-way (free), 8B-aligned

typedef float  f32x16 __attribute__((ext_vector_type(16)));
typedef __bf16 bf16x8 __attribute__((ext_vector_type(8)));

union FragU {
  uint   u[4];
  bf16x8 b;
};

__device__ __forceinline__ ushort f2bf_rne(float f) {
  uint u = __builtin_bit_cast(uint, f);
  return (ushort)((u + 0x7fffu + ((u >> 16) & 1u)) >> 16);
}

// round-half-up bf16 pack of two floats into one dword (low = f0)
__device__ __forceinline__ uint pack2bf(float f0, float f1) {
  uint u0 = __builtin_bit_cast(uint, f0) + 0x8000u;
  uint u1 = __builtin_bit_cast(uint, f1) + 0x8000u;
  return __builtin_amdgcn_perm(u1, u0, 0x07060302u);
}

__global__ __launch_bounds__(256, 2) void a2b_kernel(
    const float* __restrict__ atom, const float* __restrict__ edgef,
    const int* __restrict__ srcidx, const float* __restrict__ W,
    const float* __restrict__ bias, float* __restrict__ out) {
  __shared__ ushort WT[NODE_DIM * LDS_K];  // W^T in bf16: WT[n][k]

  // one-time W stage: fp32 [192][128] row-major -> bf16 transposed [128][196]
  for (int i = threadIdx.x; i < K_DIM * NODE_DIM; i += 256) {
    int k = i >> 7, n = i & 127;
    WT[n * LDS_K + k] = f2bf_rne(W[i]);
  }
  __syncthreads();

  const int wave = threadIdx.x >> 6;
  const int lane = threadIdx.x & 63;
  const int eloc = lane & 31;   // edge within tile (A-row m / C col index partner)
  const int half = lane >> 5;   // k-half selector
  const int ebase = (blockIdx.x * 4 + wave) * 32;  // 5000 blocks * 4 waves * 32 edges = 640000
  const int e = ebase + eloc;
  const int s = srcidx[e];
  const float* arow = atom  + (size_t)s * NODE_DIM;
  const float* erow = edgef + (size_t)e * EDGE_DIM;

  // Gather full H row fragments (fp32), all loads in flight before compute.
  // A-frag layout (32x32x16): lane holds A[m = lane&31][k = kstep*16 + (lane>>5)*8 + j]
  float4 fA[12][2];
#pragma unroll
  for (int ks = 0; ks < 12; ks++) {
    const int k0 = ks * 16 + half * 8;
    const float* p = (ks < 8) ? (arow + k0) : (erow + (k0 - 128));
    fA[ks][0] = *(const float4*)p;
    fA[ks][1] = *(const float4*)(p + 4);
  }

  f32x16 acc[4];
#pragma unroll
  for (int nt = 0; nt < 4; nt++)
#pragma unroll
    for (int i = 0; i < 16; i++) acc[nt][i] = 0.f;

#pragma unroll
  for (int ks = 0; ks < 12; ks++) {
    FragU a;
    a.u[0] = pack2bf(fA[ks][0].x, fA[ks][0].y);
    a.u[1] = pack2bf(fA[ks][0].z, fA[ks][0].w);
    a.u[2] = pack2bf(fA[ks][1].x, fA[ks][1].y);
    a.u[3] = pack2bf(fA[ks][1].z, fA[ks][1].w);
    const int kof = ks * 16 + half * 8;
#pragma unroll
    for (int nt = 0; nt < 4; nt++) {
      // B-frag: lane holds B[k = kof + j][n = nt*32 + (lane&31)] = WT[n][kof + j]
      const uint2* bp = (const uint2*)&WT[(nt * 32 + eloc) * LDS_K + kof];
      uint2 b0 = bp[0], b1 = bp[1];
      FragU bf_;
      bf_.u[0] = b0.x; bf_.u[1] = b0.y; bf_.u[2] = b1.x; bf_.u[3] = b1.y;
      acc[nt] = __builtin_amdgcn_mfma_f32_32x32x16_bf16(a.b, bf_.b, acc[nt], 0, 0, 0);
    }
  }

  // C/D layout (32x32): col = lane&31, row = (reg&3) + 8*(reg>>2) + 4*(lane>>5)
#pragma unroll
  for (int nt = 0; nt < 4; nt++) {
    const int col = nt * 32 + eloc;
    const float bb = bias[col];
#pragma unroll
    for (int r = 0; r < 16; r++) {
      const int row = (r & 3) + 8 * (r >> 2) + 4 * half;
      const float v = acc[nt][r] + bb;
      out[(size_t)(ebase + row) * NODE_DIM + col] = fmaxf(v, 0.f);
    }
  }
}

extern "C" void kernel_launch(void* const* d_in, const int* in_sizes, int n_in,
                              void* d_out, int out_size, void* d_ws, size_t ws_size,
                              hipStream_t stream) {
  const float* atom   = (const float*)d_in[0];
  const float* edgef  = (const float*)d_in[1];
  const int*   srcidx = (const int*)d_in[2];
  const float* W      = (const float*)d_in[3];
  const float* bias   = (const float*)d_in[4];
  float* out = (float*)d_out;

  dim3 grid(N_EDGES / 128);  // 5000 blocks, 4 waves * 32 edges each
  dim3 block(256);
  hipLaunchKernelGGL(a2b_kernel, grid, block, 0, stream,
                     atom, edgef, srcidx, W, bias, out);
}